// Round 2
// 982.722 us; speedup vs baseline: 1.0334x; 1.0334x over previous
//
#include <hip/hip_runtime.h>
#include <stdint.h>

#define E_ 8
#define H_ 2048
#define I_ 4096
#define T_ 1024
#define N1_ (2 * I_) /* 8192 */

typedef unsigned short ushort_t;
typedef _Float16 half_t;
typedef __attribute__((ext_vector_type(2))) _Float16 h2;
typedef __attribute__((ext_vector_type(8))) _Float16 f16x8;
typedef __attribute__((ext_vector_type(4))) float f32x4;

// pack two fp32 -> two f16 (RTZ) in one dword: 1 VALU op
__device__ __forceinline__ uint32_t pk2h(float a, float b) {
    auto r = __builtin_amdgcn_cvt_pkrtz(a, b);
    uint32_t u;
    __builtin_memcpy(&u, &r, 4);
    return u;
}

// per-K-step scale: fold gscale*blockscale/64 into a packed f16 pair
__device__ __forceinline__ h2 mk_ss(float sv) {
    half_t h = (half_t)(sv * 0.015625f); // /64: LUT stores value*64
    h2 r; r.x = h; r.y = h;
    return r;
}

// ---- dequant 4 packed words (1 byte each = 2 fp4 codes) -> 4 dwords of 2 scaled f16 ----
// LUT holds f16 high-bytes of value*64 (all normals, low byte 0):
//   codes 0..3 -> {0, 32, 64, 96}   = hi {0x00,0x50,0x54,0x56}
//   codes 4..7 -> {128,192,256,384} = hi {0x58,0x5A,0x5C,0x5E}
// sign (code bit3) ORed into the f16 high byte. One v_pk_mul_f16 by (s/64) per word.
__device__ __forceinline__ uint4 dq_quad(const int wt[4], h2 ss) {
    // gather byte0 of each word: w4 = [w3.b0, w2.b0, w1.b0, w0.b0]
    uint32_t t0 = __builtin_amdgcn_perm((uint32_t)wt[1], (uint32_t)wt[0], 0x0C0C0400u);
    uint32_t t1 = __builtin_amdgcn_perm((uint32_t)wt[3], (uint32_t)wt[2], 0x04000C0Cu);
    uint32_t w4 = t0 | t1;
    const uint32_t T_LO = 0x56545000u; // codes 0..3 (perm sel 0-3 -> 2nd operand)
    const uint32_t T_HI = 0x5E5C5A58u; // codes 4..7 (perm sel 4-7 -> 1st operand)
    uint32_t selL = w4 & 0x07070707u;
    uint32_t selH = (w4 >> 4) & 0x07070707u;
    // 4 f16-high-bytes per perm; inject signs (bit3 -> bit7 per byte)
    uint32_t hiL = __builtin_amdgcn_perm(T_HI, T_LO, selL) | ((w4 & 0x08080808u) << 4);
    uint32_t hiH = __builtin_amdgcn_perm(T_HI, T_LO, selH) | (w4 & 0x80808080u);
    // interleave into per-word f16 pairs: [hiH.b_i, 0x00, hiL.b_i, 0x00]
    uint32_t p0 = __builtin_amdgcn_perm(hiH, hiL, 0x040C000Cu);
    uint32_t p1 = __builtin_amdgcn_perm(hiH, hiL, 0x050C010Cu);
    uint32_t p2 = __builtin_amdgcn_perm(hiH, hiL, 0x060C020Cu);
    uint32_t p3 = __builtin_amdgcn_perm(hiH, hiL, 0x070C030Cu);
    uint4 q;
    h2 r0 = *(h2*)&p0 * ss; __builtin_memcpy(&q.x, &r0, 4);
    h2 r1 = *(h2*)&p1 * ss; __builtin_memcpy(&q.y, &r1, 4);
    h2 r2 = *(h2*)&p2 * ss; __builtin_memcpy(&q.z, &r2, 4);
    h2 r3 = *(h2*)&p3 * ss; __builtin_memcpy(&q.w, &r3, 4);
    return q;
}

// ==================== GEMM1: x(fp32) @ dequant(Wgu) + silu, pipelined ====================
// 512 thr, BM=256, tile = 64 I-cols (gate+up). 8 waves 4Mx2N, wave 64x(32g+32u).
// grid (I/64, T/256, C)
__global__ __launch_bounds__(512, 4) void gemm1_kernel(
    const float* __restrict__ x,
    const int* __restrict__ gup,
    const float* __restrict__ gus,
    const float* __restrict__ gscale_p,
    ushort_t* __restrict__ inter,
    int e0) {
    __shared__ __align__(16) ushort_t As[2][256 * 40];
    __shared__ __align__(16) ushort_t Bs[2][128 * 40];

    const int tid = threadIdx.x;
    const int lane = tid & 63, wv = tid >> 6;
    const int quad = lane >> 4, c16 = lane & 15;
    const int mw = wv >> 1, nw = wv & 1;
    const int zloc = blockIdx.z, e = e0 + zloc;
    const int mBase = blockIdx.y * 256, nTile = blockIdx.x;
    const float gsc = gscale_p[0];

    const int bn = tid & 127, kq = tid >> 7;
    const int colg = nTile * 64 + (bn & 63) + ((bn >> 6) << 12);
    const int* bptr = gup + (size_t)e * (H_ / 2) * N1_ + (size_t)(kq * 4) * N1_ + colg;
    const float* sptr = gus + (size_t)e * (H_ / 16) * N1_ + (size_t)(kq >> 1) * N1_ + colg;

    const int arow = tid >> 3, seg = tid & 7;
    const float* ap = x + (size_t)(e * T_ + mBase + arow) * H_ + seg * 4;

    f32x4 accg[4][2], accu[4][2];
    const f32x4 z4 = {0.f, 0.f, 0.f, 0.f};
#pragma unroll
    for (int f = 0; f < 4; ++f)
#pragma unroll
        for (int b = 0; b < 2; ++b) { accg[f][b] = z4; accu[f][b] = z4; }

    float4 fa[4]; int wt[4]; float sv;
    // ---- prologue: tile 0 ----
#pragma unroll
    for (int p = 0; p < 4; ++p) fa[p] = *(const float4*)(ap + (size_t)(p * 64) * H_);
#pragma unroll
    for (int i = 0; i < 4; ++i) wt[i] = bptr[(size_t)i * N1_];
    sv = sptr[0] * gsc;
    {
#pragma unroll
        for (int p = 0; p < 4; ++p) {
            uint2 d; d.x = pk2h(fa[p].x, fa[p].y); d.y = pk2h(fa[p].z, fa[p].w);
            *(uint2*)(&As[0][(arow + p * 64) * 40 + seg * 4]) = d;
        }
        uint4 q = dq_quad(wt, mk_ss(sv));
        *(uint4*)(&Bs[0][bn * 40 + kq * 8]) = q;
    }
    __syncthreads();

    for (int kt = 0; kt < H_ / 32 - 1; ++kt) {
        const int cur = kt & 1, nxt = cur ^ 1;
        // ---- prefetch tile kt+1 into registers ----
#pragma unroll
        for (int p = 0; p < 4; ++p)
            fa[p] = *(const float4*)(ap + (size_t)(p * 64) * H_ + (kt + 1) * 32);
        const int* bp = bptr + (size_t)(kt + 1) * 16 * N1_;
#pragma unroll
        for (int i = 0; i < 4; ++i) wt[i] = bp[(size_t)i * N1_];
        sv = sptr[(size_t)(kt + 1) * 2 * N1_] * gsc;

        // ---- consume current LDS tile ----
        f16x8 bg0 = *(const f16x8*)(&Bs[cur][(nw * 32 + c16) * 40 + quad * 8]);
        f16x8 bg1 = *(const f16x8*)(&Bs[cur][(nw * 32 + 16 + c16) * 40 + quad * 8]);
        f16x8 bu0 = *(const f16x8*)(&Bs[cur][(64 + nw * 32 + c16) * 40 + quad * 8]);
        f16x8 bu1 = *(const f16x8*)(&Bs[cur][(64 + nw * 32 + 16 + c16) * 40 + quad * 8]);
#pragma unroll
        for (int f = 0; f < 4; ++f) {
            f16x8 af = *(const f16x8*)(&As[cur][(mw * 64 + f * 16 + c16) * 40 + quad * 8]);
            accg[f][0] = __builtin_amdgcn_mfma_f32_16x16x32_f16(af, bg0, accg[f][0], 0, 0, 0);
            accg[f][1] = __builtin_amdgcn_mfma_f32_16x16x32_f16(af, bg1, accg[f][1], 0, 0, 0);
            accu[f][0] = __builtin_amdgcn_mfma_f32_16x16x32_f16(af, bu0, accu[f][0], 0, 0, 0);
            accu[f][1] = __builtin_amdgcn_mfma_f32_16x16x32_f16(af, bu1, accu[f][1], 0, 0, 0);
        }

        // ---- stage prefetched tile into other buffer ----
#pragma unroll
        for (int p = 0; p < 4; ++p) {
            uint2 d; d.x = pk2h(fa[p].x, fa[p].y); d.y = pk2h(fa[p].z, fa[p].w);
            *(uint2*)(&As[nxt][(arow + p * 64) * 40 + seg * 4]) = d;
        }
        uint4 q = dq_quad(wt, mk_ss(sv));
        *(uint4*)(&Bs[nxt][bn * 40 + kq * 8]) = q;
        __syncthreads();
    }

    // ---- last tile (buffer 1) ----
    {
        const int cur = (H_ / 32 - 1) & 1;
        f16x8 bg0 = *(const f16x8*)(&Bs[cur][(nw * 32 + c16) * 40 + quad * 8]);
        f16x8 bg1 = *(const f16x8*)(&Bs[cur][(nw * 32 + 16 + c16) * 40 + quad * 8]);
        f16x8 bu0 = *(const f16x8*)(&Bs[cur][(64 + nw * 32 + c16) * 40 + quad * 8]);
        f16x8 bu1 = *(const f16x8*)(&Bs[cur][(64 + nw * 32 + 16 + c16) * 40 + quad * 8]);
#pragma unroll
        for (int f = 0; f < 4; ++f) {
            f16x8 af = *(const f16x8*)(&As[cur][(mw * 64 + f * 16 + c16) * 40 + quad * 8]);
            accg[f][0] = __builtin_amdgcn_mfma_f32_16x16x32_f16(af, bg0, accg[f][0], 0, 0, 0);
            accg[f][1] = __builtin_amdgcn_mfma_f32_16x16x32_f16(af, bg1, accg[f][1], 0, 0, 0);
            accu[f][0] = __builtin_amdgcn_mfma_f32_16x16x32_f16(af, bu0, accu[f][0], 0, 0, 0);
            accu[f][1] = __builtin_amdgcn_mfma_f32_16x16x32_f16(af, bu1, accu[f][1], 0, 0, 0);
        }
    }

    // epilogue: inter = up * silu(gate), stored as f16
    ushort_t* ip = inter + (size_t)zloc * T_ * I_;
#pragma unroll
    for (int f = 0; f < 4; ++f)
#pragma unroll
        for (int b = 0; b < 2; ++b)
#pragma unroll
            for (int r = 0; r < 4; ++r) {
                int row = mBase + mw * 64 + f * 16 + quad * 4 + r;
                int col = nTile * 64 + nw * 32 + b * 16 + c16;
                float g = accg[f][b][r];
                float u = accu[f][b][r];
                float v = u * g / (1.f + __expf(-g));
                half_t hv = (half_t)v;
                ushort_t hu;
                __builtin_memcpy(&hu, &hv, 2);
                ip[(size_t)row * I_ + col] = hu;
            }
}

// ==================== GEMM2: inter(f16) @ dequant(Wd) -> fp32, pipelined ====================
// 512 thr, BM=256, BN=128. 8 waves 4Mx2N, wave 64x64. grid (H/128, T/256, C)
__global__ __launch_bounds__(512, 4) void gemm2_kernel(
    const ushort_t* __restrict__ inter,
    const int* __restrict__ dp,
    const float* __restrict__ dsc,
    const float* __restrict__ gscale_p,
    float* __restrict__ out,
    int e0) {
    __shared__ __align__(16) ushort_t As[2][256 * 40];
    __shared__ __align__(16) ushort_t Bs[2][128 * 40];

    const int tid = threadIdx.x;
    const int lane = tid & 63, wv = tid >> 6;
    const int quad = lane >> 4, c16 = lane & 15;
    const int mw = wv >> 1, nw = wv & 1;
    const int zloc = blockIdx.z, e = e0 + zloc;
    const int mBase = blockIdx.y * 256, nBase = blockIdx.x * 128;
    const float gsc = gscale_p[0];

    const int bn = tid & 127, kq = tid >> 7;
    const int col = nBase + bn;
    const int* bptr = dp + (size_t)e * (I_ / 2) * H_ + (size_t)(kq * 4) * H_ + col;
    const float* sptr = dsc + (size_t)e * (I_ / 16) * H_ + (size_t)(kq >> 1) * H_ + col;

    const int arow = tid >> 2, seg = tid & 3;
    const ushort_t* ap = inter + (size_t)(zloc * T_ + mBase + arow) * I_ + seg * 8;

    f32x4 acc[4][4];
    const f32x4 z4 = {0.f, 0.f, 0.f, 0.f};
#pragma unroll
    for (int f = 0; f < 4; ++f)
#pragma unroll
        for (int b = 0; b < 4; ++b) acc[f][b] = z4;

    uint4 va[2]; int wt[4]; float sv;
    // ---- prologue: tile 0 ----
#pragma unroll
    for (int p = 0; p < 2; ++p) va[p] = *(const uint4*)(ap + (size_t)(p * 128) * I_);
#pragma unroll
    for (int i = 0; i < 4; ++i) wt[i] = bptr[(size_t)i * H_];
    sv = sptr[0] * gsc;
    {
#pragma unroll
        for (int p = 0; p < 2; ++p)
            *(uint4*)(&As[0][(arow + p * 128) * 40 + seg * 8]) = va[p];
        uint4 q = dq_quad(wt, mk_ss(sv));
        *(uint4*)(&Bs[0][bn * 40 + kq * 8]) = q;
    }
    __syncthreads();

    for (int kt = 0; kt < I_ / 32 - 1; ++kt) {
        const int cur = kt & 1, nxt = cur ^ 1;
        // ---- prefetch tile kt+1 ----
#pragma unroll
        for (int p = 0; p < 2; ++p)
            va[p] = *(const uint4*)(ap + (size_t)(p * 128) * I_ + (kt + 1) * 32);
        const int* bp = bptr + (size_t)(kt + 1) * 16 * H_;
#pragma unroll
        for (int i = 0; i < 4; ++i) wt[i] = bp[(size_t)i * H_];
        sv = sptr[(size_t)(kt + 1) * 2 * H_] * gsc;

        // ---- consume current ----
        f16x8 bfr[4];
#pragma unroll
        for (int b = 0; b < 4; ++b)
            bfr[b] = *(const f16x8*)(&Bs[cur][(nw * 64 + b * 16 + c16) * 40 + quad * 8]);
#pragma unroll
        for (int f = 0; f < 4; ++f) {
            f16x8 af = *(const f16x8*)(&As[cur][(mw * 64 + f * 16 + c16) * 40 + quad * 8]);
#pragma unroll
            for (int b = 0; b < 4; ++b)
                acc[f][b] = __builtin_amdgcn_mfma_f32_16x16x32_f16(af, bfr[b], acc[f][b], 0, 0, 0);
        }

        // ---- stage next ----
#pragma unroll
        for (int p = 0; p < 2; ++p)
            *(uint4*)(&As[nxt][(arow + p * 128) * 40 + seg * 8]) = va[p];
        uint4 q = dq_quad(wt, mk_ss(sv));
        *(uint4*)(&Bs[nxt][bn * 40 + kq * 8]) = q;
        __syncthreads();
    }

    // ---- last tile ----
    {
        const int cur = (I_ / 32 - 1) & 1;
        f16x8 bfr[4];
#pragma unroll
        for (int b = 0; b < 4; ++b)
            bfr[b] = *(const f16x8*)(&Bs[cur][(nw * 64 + b * 16 + c16) * 40 + quad * 8]);
#pragma unroll
        for (int f = 0; f < 4; ++f) {
            f16x8 af = *(const f16x8*)(&As[cur][(mw * 64 + f * 16 + c16) * 40 + quad * 8]);
#pragma unroll
            for (int b = 0; b < 4; ++b)
                acc[f][b] = __builtin_amdgcn_mfma_f32_16x16x32_f16(af, bfr[b], acc[f][b], 0, 0, 0);
        }
    }

#pragma unroll
    for (int f = 0; f < 4; ++f)
#pragma unroll
        for (int b = 0; b < 4; ++b)
#pragma unroll
            for (int r = 0; r < 4; ++r) {
                int row = mBase + mw * 64 + f * 16 + quad * 4 + r;
                int c = nBase + nw * 64 + b * 16 + c16;
                out[(size_t)(e * T_ + row) * H_ + c] = acc[f][b][r];
            }
}

extern "C" void kernel_launch(void* const* d_in, const int* in_sizes, int n_in,
                              void* d_out, int out_size, void* d_ws, size_t ws_size,
                              hipStream_t stream) {
    const float* x = (const float*)d_in[0];
    const int* gup = (const int*)d_in[1];
    const float* gus = (const float*)d_in[2];
    const float* gug = (const float*)d_in[3];
    const int* dp = (const int*)d_in[4];
    const float* dsc = (const float*)d_in[5];
    const float* dg = (const float*)d_in[6];
    float* out = (float*)d_out;
    ushort_t* inter = (ushort_t*)d_ws;

    const size_t per_e = (size_t)T_ * I_ * 2;
    int C = 8;
    if (ws_size < 8 * per_e) C = (ws_size >= 4 * per_e) ? 4 : (ws_size >= 2 * per_e) ? 2 : 1;

    for (int e0 = 0; e0 < E_; e0 += C) {
        gemm1_kernel<<<dim3(I_ / 64, T_ / 256, C), 512, 0, stream>>>(x, gup, gus, gug, inter, e0);
        gemm2_kernel<<<dim3(H_ / 128, T_ / 256, C), 512, 0, stream>>>(inter, dp, dsc, dg, out, e0);
    }
}

// Round 5
// 970.537 us; speedup vs baseline: 1.0464x; 1.0126x over previous
//
#include <hip/hip_runtime.h>
#include <stdint.h>

#define E_ 8
#define H_ 2048
#define I_ 4096
#define T_ 1024
#define N1_ (2 * I_) /* 8192 */

typedef unsigned short ushort_t;
typedef _Float16 half_t;
typedef __attribute__((ext_vector_type(2))) _Float16 h2;
typedef __attribute__((ext_vector_type(8))) _Float16 f16x8;
typedef __attribute__((ext_vector_type(4))) float f32x4;

// pack two fp32 -> two f16 (RTZ) in one dword: 1 VALU op
__device__ __forceinline__ uint32_t pk2h(float a, float b) {
    auto r = __builtin_amdgcn_cvt_pkrtz(a, b);
    uint32_t u;
    __builtin_memcpy(&u, &r, 4);
    return u;
}

// per-K-step scale: fold gscale*blockscale/64 into a packed f16 pair
__device__ __forceinline__ h2 mk_ss(float sv) {
    half_t h = (half_t)(sv * 0.015625f); // /64: LUT stores value*64
    h2 r; r.x = h; r.y = h;
    return r;
}

// ---- dequant 4 packed words (1 byte each = 2 fp4 codes) -> 4 dwords of 2 scaled f16 ----
__device__ __forceinline__ uint4 dq_quad(const int wt[4], h2 ss) {
    uint32_t t0 = __builtin_amdgcn_perm((uint32_t)wt[1], (uint32_t)wt[0], 0x0C0C0400u);
    uint32_t t1 = __builtin_amdgcn_perm((uint32_t)wt[3], (uint32_t)wt[2], 0x04000C0Cu);
    uint32_t w4 = t0 | t1;
    const uint32_t T_LO = 0x56545000u; // codes 0..3 f16-hi of val*64
    const uint32_t T_HI = 0x5E5C5A58u; // codes 4..7
    uint32_t selL = w4 & 0x07070707u;
    uint32_t selH = (w4 >> 4) & 0x07070707u;
    uint32_t hiL = __builtin_amdgcn_perm(T_HI, T_LO, selL) | ((w4 & 0x08080808u) << 4);
    uint32_t hiH = __builtin_amdgcn_perm(T_HI, T_LO, selH) | (w4 & 0x80808080u);
    uint32_t p0 = __builtin_amdgcn_perm(hiH, hiL, 0x040C000Cu);
    uint32_t p1 = __builtin_amdgcn_perm(hiH, hiL, 0x050C010Cu);
    uint32_t p2 = __builtin_amdgcn_perm(hiH, hiL, 0x060C020Cu);
    uint32_t p3 = __builtin_amdgcn_perm(hiH, hiL, 0x070C030Cu);
    uint4 q;
    h2 r0 = *(h2*)&p0 * ss; __builtin_memcpy(&q.x, &r0, 4);
    h2 r1 = *(h2*)&p1 * ss; __builtin_memcpy(&q.y, &r1, 4);
    h2 r2 = *(h2*)&p2 * ss; __builtin_memcpy(&q.z, &r2, 4);
    h2 r3 = *(h2*)&p3 * ss; __builtin_memcpy(&q.w, &r3, 4);
    return q;
}

// ==================== GEMM1: x(fp32) @ dequant(Wgu) + silu, pipelined ====================
// 512 thr, BM=256, tile = 64 I-cols (gate+up). 8 waves 4Mx2N.
// B-staging remapped: wave = 16 cols x 4 kq -> 2-way LDS write (was 8-way).
__global__ __launch_bounds__(512, 4) void gemm1_kernel(
    const float* __restrict__ x,
    const int* __restrict__ gup,
    const float* __restrict__ gus,
    const float* __restrict__ gscale_p,
    ushort_t* __restrict__ inter,
    int e0) {
    __shared__ __align__(16) ushort_t As[2][256 * 40];
    __shared__ __align__(16) ushort_t Bs[2][128 * 40];

    const int tid = threadIdx.x;
    const int lane = tid & 63, wv = tid >> 6;
    const int quad = lane >> 4, c16 = lane & 15;
    const int mw = wv >> 1, nw = wv & 1;
    const int zloc = blockIdx.z, e = e0 + zloc;
    const int mBase = blockIdx.y * 256, nTile = blockIdx.x;
    const float gsc = gscale_p[0];

    // B staging: kq in-wave, 16 cols per wave (bank-conflict-free b128 writes)
    const int kq = (tid >> 4) & 3;
    const int bn = (tid & 15) | ((tid >> 6) << 4);
    const int colg = nTile * 64 + (bn & 63) + ((bn >> 6) << 12);
    const int* bptr = gup + (size_t)e * (H_ / 2) * N1_ + (size_t)(kq * 4) * N1_ + colg;
    const float* sptr = gus + (size_t)e * (H_ / 16) * N1_ + (size_t)(kq >> 1) * N1_ + colg;

    // A staging: 128 rows x 4 segs, uint4 LDS writes (2-way, free)
    const int arow = tid >> 2, seg = tid & 3;
    const float* ap = x + (size_t)(e * T_ + mBase + arow) * H_ + seg * 8;

    f32x4 accg[4][2], accu[4][2];
    const f32x4 z4 = {0.f, 0.f, 0.f, 0.f};
#pragma unroll
    for (int f = 0; f < 4; ++f)
#pragma unroll
        for (int b = 0; b < 2; ++b) { accg[f][b] = z4; accu[f][b] = z4; }

    float4 fa[4]; int wt[4]; float sv;
    // ---- prologue: tile 0 ----
    fa[0] = *(const float4*)(ap);
    fa[1] = *(const float4*)(ap + 4);
    fa[2] = *(const float4*)(ap + (size_t)128 * H_);
    fa[3] = *(const float4*)(ap + (size_t)128 * H_ + 4);
#pragma unroll
    for (int i = 0; i < 4; ++i) wt[i] = bptr[(size_t)i * N1_];
    sv = sptr[0] * gsc;
    {
        uint4 d0, d1;
        d0.x = pk2h(fa[0].x, fa[0].y); d0.y = pk2h(fa[0].z, fa[0].w);
        d0.z = pk2h(fa[1].x, fa[1].y); d0.w = pk2h(fa[1].z, fa[1].w);
        d1.x = pk2h(fa[2].x, fa[2].y); d1.y = pk2h(fa[2].z, fa[2].w);
        d1.z = pk2h(fa[3].x, fa[3].y); d1.w = pk2h(fa[3].z, fa[3].w);
        *(uint4*)(&As[0][arow * 40 + seg * 8]) = d0;
        *(uint4*)(&As[0][(arow + 128) * 40 + seg * 8]) = d1;
        uint4 q = dq_quad(wt, mk_ss(sv));
        *(uint4*)(&Bs[0][bn * 40 + kq * 8]) = q;
    }
    __syncthreads();

    for (int kt = 0; kt < H_ / 32 - 1; ++kt) {
        const int cur = kt & 1, nxt = cur ^ 1;
        // ---- prefetch tile kt+1 into registers ----
        fa[0] = *(const float4*)(ap + (kt + 1) * 32);
        fa[1] = *(const float4*)(ap + (kt + 1) * 32 + 4);
        fa[2] = *(const float4*)(ap + (size_t)128 * H_ + (kt + 1) * 32);
        fa[3] = *(const float4*)(ap + (size_t)128 * H_ + (kt + 1) * 32 + 4);
        const int* bp = bptr + (size_t)(kt + 1) * 16 * N1_;
#pragma unroll
        for (int i = 0; i < 4; ++i) wt[i] = bp[(size_t)i * N1_];
        sv = sptr[(size_t)(kt + 1) * 2 * N1_] * gsc;

        // ---- consume current LDS tile ----
        f16x8 bg0 = *(const f16x8*)(&Bs[cur][(nw * 32 + c16) * 40 + quad * 8]);
        f16x8 bg1 = *(const f16x8*)(&Bs[cur][(nw * 32 + 16 + c16) * 40 + quad * 8]);
        f16x8 bu0 = *(const f16x8*)(&Bs[cur][(64 + nw * 32 + c16) * 40 + quad * 8]);
        f16x8 bu1 = *(const f16x8*)(&Bs[cur][(64 + nw * 32 + 16 + c16) * 40 + quad * 8]);
#pragma unroll
        for (int f = 0; f < 4; ++f) {
            f16x8 af = *(const f16x8*)(&As[cur][(mw * 64 + f * 16 + c16) * 40 + quad * 8]);
            accg[f][0] = __builtin_amdgcn_mfma_f32_16x16x32_f16(af, bg0, accg[f][0], 0, 0, 0);
            accg[f][1] = __builtin_amdgcn_mfma_f32_16x16x32_f16(af, bg1, accg[f][1], 0, 0, 0);
            accu[f][0] = __builtin_amdgcn_mfma_f32_16x16x32_f16(af, bu0, accu[f][0], 0, 0, 0);
            accu[f][1] = __builtin_amdgcn_mfma_f32_16x16x32_f16(af, bu1, accu[f][1], 0, 0, 0);
        }

        // ---- stage prefetched tile into other buffer ----
        {
            uint4 d0, d1;
            d0.x = pk2h(fa[0].x, fa[0].y); d0.y = pk2h(fa[0].z, fa[0].w);
            d0.z = pk2h(fa[1].x, fa[1].y); d0.w = pk2h(fa[1].z, fa[1].w);
            d1.x = pk2h(fa[2].x, fa[2].y); d1.y = pk2h(fa[2].z, fa[2].w);
            d1.z = pk2h(fa[3].x, fa[3].y); d1.w = pk2h(fa[3].z, fa[3].w);
            *(uint4*)(&As[nxt][arow * 40 + seg * 8]) = d0;
            *(uint4*)(&As[nxt][(arow + 128) * 40 + seg * 8]) = d1;
            uint4 q = dq_quad(wt, mk_ss(sv));
            *(uint4*)(&Bs[nxt][bn * 40 + kq * 8]) = q;
        }
        __syncthreads();
    }

    // ---- last tile ----
    {
        const int cur = (H_ / 32 - 1) & 1;
        f16x8 bg0 = *(const f16x8*)(&Bs[cur][(nw * 32 + c16) * 40 + quad * 8]);
        f16x8 bg1 = *(const f16x8*)(&Bs[cur][(nw * 32 + 16 + c16) * 40 + quad * 8]);
        f16x8 bu0 = *(const f16x8*)(&Bs[cur][(64 + nw * 32 + c16) * 40 + quad * 8]);
        f16x8 bu1 = *(const f16x8*)(&Bs[cur][(64 + nw * 32 + 16 + c16) * 40 + quad * 8]);
#pragma unroll
        for (int f = 0; f < 4; ++f) {
            f16x8 af = *(const f16x8*)(&As[cur][(mw * 64 + f * 16 + c16) * 40 + quad * 8]);
            accg[f][0] = __builtin_amdgcn_mfma_f32_16x16x32_f16(af, bg0, accg[f][0], 0, 0, 0);
            accg[f][1] = __builtin_amdgcn_mfma_f32_16x16x32_f16(af, bg1, accg[f][1], 0, 0, 0);
            accu[f][0] = __builtin_amdgcn_mfma_f32_16x16x32_f16(af, bu0, accu[f][0], 0, 0, 0);
            accu[f][1] = __builtin_amdgcn_mfma_f32_16x16x32_f16(af, bu1, accu[f][1], 0, 0, 0);
        }
    }

    // epilogue: inter = up * silu(gate), stored as f16
    ushort_t* ip = inter + (size_t)zloc * T_ * I_;
#pragma unroll
    for (int f = 0; f < 4; ++f)
#pragma unroll
        for (int b = 0; b < 2; ++b)
#pragma unroll
            for (int r = 0; r < 4; ++r) {
                int row = mBase + mw * 64 + f * 16 + quad * 4 + r;
                int col = nTile * 64 + nw * 32 + b * 16 + c16;
                float g = accg[f][b][r];
                float u = accu[f][b][r];
                float v = u * g / (1.f + __expf(-g));
                half_t hv = (half_t)v;
                ushort_t hu;
                __builtin_memcpy(&hu, &hv, 2);
                ip[(size_t)row * I_ + col] = hu;
            }
}

// ==================== GEMM2: inter(f16) @ dequant(Wd) -> fp32, pipelined ====================
// 512 thr, BM=256, BN=128. 8 waves 4Mx2N. B-staging remapped like gemm1.
__global__ __launch_bounds__(512, 4) void gemm2_kernel(
    const ushort_t* __restrict__ inter,
    const int* __restrict__ dp,
    const float* __restrict__ dsc,
    const float* __restrict__ gscale_p,
    float* __restrict__ out,
    int e0) {
    __shared__ __align__(16) ushort_t As[2][256 * 40];
    __shared__ __align__(16) ushort_t Bs[2][128 * 40];

    const int tid = threadIdx.x;
    const int lane = tid & 63, wv = tid >> 6;
    const int quad = lane >> 4, c16 = lane & 15;
    const int mw = wv >> 1, nw = wv & 1;
    const int zloc = blockIdx.z, e = e0 + zloc;
    const int mBase = blockIdx.y * 256, nBase = blockIdx.x * 128;
    const float gsc = gscale_p[0];

    const int kq = (tid >> 4) & 3;
    const int bn = (tid & 15) | ((tid >> 6) << 4);
    const int col = nBase + bn;
    const int* bptr = dp + (size_t)e * (I_ / 2) * H_ + (size_t)(kq * 4) * H_ + col;
    const float* sptr = dsc + (size_t)e * (I_ / 16) * H_ + (size_t)(kq >> 1) * H_ + col;

    const int arow = tid >> 2, seg = tid & 3;
    const ushort_t* ap = inter + (size_t)(zloc * T_ + mBase + arow) * I_ + seg * 8;

    f32x4 acc[4][4];
    const f32x4 z4 = {0.f, 0.f, 0.f, 0.f};
#pragma unroll
    for (int f = 0; f < 4; ++f)
#pragma unroll
        for (int b = 0; b < 4; ++b) acc[f][b] = z4;

    uint4 va[2]; int wt[4]; float sv;
    // ---- prologue: tile 0 ----
#pragma unroll
    for (int p = 0; p < 2; ++p) va[p] = *(const uint4*)(ap + (size_t)(p * 128) * I_);
#pragma unroll
    for (int i = 0; i < 4; ++i) wt[i] = bptr[(size_t)i * H_];
    sv = sptr[0] * gsc;
    {
#pragma unroll
        for (int p = 0; p < 2; ++p)
            *(uint4*)(&As[0][(arow + p * 128) * 40 + seg * 8]) = va[p];
        uint4 q = dq_quad(wt, mk_ss(sv));
        *(uint4*)(&Bs[0][bn * 40 + kq * 8]) = q;
    }
    __syncthreads();

    for (int kt = 0; kt < I_ / 32 - 1; ++kt) {
        const int cur = kt & 1, nxt = cur ^ 1;
        // ---- prefetch tile kt+1 ----
#pragma unroll
        for (int p = 0; p < 2; ++p)
            va[p] = *(const uint4*)(ap + (size_t)(p * 128) * I_ + (kt + 1) * 32);
        const int* bp = bptr + (size_t)(kt + 1) * 16 * H_;
#pragma unroll
        for (int i = 0; i < 4; ++i) wt[i] = bp[(size_t)i * H_];
        sv = sptr[(size_t)(kt + 1) * 2 * H_] * gsc;

        // ---- consume current ----
        f16x8 bfr[4];
#pragma unroll
        for (int b = 0; b < 4; ++b)
            bfr[b] = *(const f16x8*)(&Bs[cur][(nw * 64 + b * 16 + c16) * 40 + quad * 8]);
#pragma unroll
        for (int f = 0; f < 4; ++f) {
            f16x8 af = *(const f16x8*)(&As[cur][(mw * 64 + f * 16 + c16) * 40 + quad * 8]);
#pragma unroll
            for (int b = 0; b < 4; ++b)
                acc[f][b] = __builtin_amdgcn_mfma_f32_16x16x32_f16(af, bfr[b], acc[f][b], 0, 0, 0);
        }

        // ---- stage next ----
#pragma unroll
        for (int p = 0; p < 2; ++p)
            *(uint4*)(&As[nxt][(arow + p * 128) * 40 + seg * 8]) = va[p];
        uint4 q = dq_quad(wt, mk_ss(sv));
        *(uint4*)(&Bs[nxt][bn * 40 + kq * 8]) = q;
        __syncthreads();
    }

    // ---- last tile ----
    {
        const int cur = (I_ / 32 - 1) & 1;
        f16x8 bfr[4];
#pragma unroll
        for (int b = 0; b < 4; ++b)
            bfr[b] = *(const f16x8*)(&Bs[cur][(nw * 64 + b * 16 + c16) * 40 + quad * 8]);
#pragma unroll
        for (int f = 0; f < 4; ++f) {
            f16x8 af = *(const f16x8*)(&As[cur][(mw * 64 + f * 16 + c16) * 40 + quad * 8]);
#pragma unroll
            for (int b = 0; b < 4; ++b)
                acc[f][b] = __builtin_amdgcn_mfma_f32_16x16x32_f16(af, bfr[b], acc[f][b], 0, 0, 0);
        }
    }

#pragma unroll
    for (int f = 0; f < 4; ++f)
#pragma unroll
        for (int b = 0; b < 4; ++b)
#pragma unroll
            for (int r = 0; r < 4; ++r) {
                int row = mBase + mw * 64 + f * 16 + quad * 4 + r;
                int c = nBase + nw * 64 + b * 16 + c16;
                out[(size_t)(e * T_ + row) * H_ + c] = acc[f][b][r];
            }
}

extern "C" void kernel_launch(void* const* d_in, const int* in_sizes, int n_in,
                              void* d_out, int out_size, void* d_ws, size_t ws_size,
                              hipStream_t stream) {
    const float* x = (const float*)d_in[0];
    const int* gup = (const int*)d_in[1];
    const float* gus = (const float*)d_in[2];
    const float* gug = (const float*)d_in[3];
    const int* dp = (const int*)d_in[4];
    const float* dsc = (const float*)d_in[5];
    const float* dg = (const float*)d_in[6];
    float* out = (float*)d_out;
    ushort_t* inter = (ushort_t*)d_ws;

    const size_t per_e = (size_t)T_ * I_ * 2;
    int C = 8;
    if (ws_size < 8 * per_e) C = (ws_size >= 4 * per_e) ? 4 : (ws_size >= 2 * per_e) ? 2 : 1;

    for (int e0 = 0; e0 < E_; e0 += C) {
        gemm1_kernel<<<dim3(I_ / 64, T_ / 256, C), 512, 0, stream>>>(x, gup, gus, gug, inter, e0);
        gemm2_kernel<<<dim3(H_ / 128, T_ / 256, C), 512, 0, stream>>>(inter, dp, dsc, dg, out, e0);
    }
}